// Round 18
// baseline (164.627 us; speedup 1.0000x reference)
//
#include <hip/hip_runtime.h>
#include <math.h>

#define BATCH 64
#define NN 512
#define MM 512
#define DD 128
#define BIGF 1e30f
#define KLOG2E 1.442695040888963f
#define LN2F   0.693147180559945f
#define BIGK   (BIGF * KLOG2E)

#define NA4 640         // quad-antidiagonal lines (0..638 valid, padded)
#define NP4 128         // quad-rows per batch

typedef __attribute__((ext_vector_type(2))) float f32x2;
typedef __attribute__((ext_vector_type(4))) float f32x4;
typedef __attribute__((ext_vector_type(8))) short s16x8;

// ---------------------------------------------------------------------------
// Kernel 1: FUSED cost GEMM (bf16 MFMA cross-term + exact fp32 row norms).
// Epilogue now emits QUAD-diagonal layout:
//   Cd4[b][a4][iq] = f32x4{ C[4iq..4iq+3][a4-iq] } * (log2e/D),  a4 = iq + j
// so the 2-wave DTW kernel loads one dwordx4/lane, 1KB contiguous per wave.
// ---------------------------------------------------------------------------
__device__ __forceinline__ unsigned short f2bf(float f) {
    unsigned u = __float_as_uint(f);
    u += 0x7FFFu + ((u >> 16) & 1u);   // round-to-nearest-even
    return (unsigned short)(u >> 16);
}

#define LSI4(A, IQ) ((A) * 16 + ((IQ) ^ ((A) & 15)))

__global__ __launch_bounds__(256) void cost_diag_mfma(const float* __restrict__ X,
                                                      const float* __restrict__ Y,
                                                      f32x4* __restrict__ Cd) {
    __shared__ alignas(16) short smem[2 * 64 * 128];   // 32 KB: Xbf | Ybf
    __shared__ float x2s[64];
    __shared__ float y2s[64];
    short* Xbf = smem;
    short* Ybf = smem + 64 * 128;
    f32x4* Ls4 = (f32x4*)smem;                         // reused post-MFMA (~20 KB)

    int b  = blockIdx.z;
    int ti = blockIdx.y * 64;
    int tj = blockIdx.x * 64;
    int t  = threadIdx.x;
    int l  = t & 63;
    int w  = t >> 6;

    const float* Xb = X + ((size_t)b * NN + ti) * DD;
    const float* Yb = Y + ((size_t)b * MM + tj) * DD;

    int rw  = t >> 4;          // 0..15
    int k8l = t & 15;          // 16B slot (8 bf16)
    float xs_acc[4], ys_acc[4];
    #pragma unroll
    for (int it = 0; it < 4; ++it) {
        int r = rw + it * 16;
        const float* sx = Xb + (size_t)r * DD + k8l * 8;
        const float* sy = Yb + (size_t)r * DD + k8l * 8;
        float4 x0 = *(const float4*)sx;
        float4 x1 = *(const float4*)(sx + 4);
        float4 y0 = *(const float4*)sy;
        float4 y1 = *(const float4*)(sy + 4);
        xs_acc[it] = x0.x*x0.x + x0.y*x0.y + x0.z*x0.z + x0.w*x0.w
                   + x1.x*x1.x + x1.y*x1.y + x1.z*x1.z + x1.w*x1.w;
        ys_acc[it] = y0.x*y0.x + y0.y*y0.y + y0.z*y0.z + y0.w*y0.w
                   + y1.x*y1.x + y1.y*y1.y + y1.z*y1.z + y1.w*y1.w;
        s16x8 xv, yv;
        xv[0] = (short)f2bf(x0.x); xv[1] = (short)f2bf(x0.y);
        xv[2] = (short)f2bf(x0.z); xv[3] = (short)f2bf(x0.w);
        xv[4] = (short)f2bf(x1.x); xv[5] = (short)f2bf(x1.y);
        xv[6] = (short)f2bf(x1.z); xv[7] = (short)f2bf(x1.w);
        yv[0] = (short)f2bf(y0.x); yv[1] = (short)f2bf(y0.y);
        yv[2] = (short)f2bf(y0.z); yv[3] = (short)f2bf(y0.w);
        yv[4] = (short)f2bf(y1.x); yv[5] = (short)f2bf(y1.y);
        yv[6] = (short)f2bf(y1.z); yv[7] = (short)f2bf(y1.w);
        int sw = (r * 16 + (k8l ^ (r & 7))) * 8;
        *(s16x8*)&Xbf[sw] = xv;
        *(s16x8*)&Ybf[sw] = yv;
    }
    #pragma unroll
    for (int it = 0; it < 4; ++it) {
        float xs = xs_acc[it], ys = ys_acc[it];
        #pragma unroll
        for (int m = 8; m >= 1; m >>= 1) {
            xs += __shfl_xor(xs, m, 16);
            ys += __shfl_xor(ys, m, 16);
        }
        if (k8l == 0) { x2s[rw + it * 16] = xs; y2s[rw + it * 16] = ys; }
    }
    __syncthreads();

    f32x4 acc0 = {0.f,0.f,0.f,0.f}, acc1 = acc0, acc2 = acc0, acc3 = acc0;
    int ar = 16 * w + (l & 15);
    int kb = l >> 4;           // 0..3
    int c0 = l & 15;
    #pragma unroll
    for (int kk = 0; kk < 4; ++kk) {
        int k8 = kk * 4 + kb;
        s16x8 af = *(const s16x8*)&Xbf[(ar * 16 + (k8 ^ (ar & 7))) * 8];
        s16x8 b0 = *(const s16x8*)&Ybf[((c0     ) * 16 + (k8 ^ ((c0     ) & 7))) * 8];
        s16x8 b1 = *(const s16x8*)&Ybf[((c0 + 16) * 16 + (k8 ^ ((c0 + 16) & 7))) * 8];
        s16x8 b2 = *(const s16x8*)&Ybf[((c0 + 32) * 16 + (k8 ^ ((c0 + 32) & 7))) * 8];
        s16x8 b3 = *(const s16x8*)&Ybf[((c0 + 48) * 16 + (k8 ^ ((c0 + 48) & 7))) * 8];
        acc0 = __builtin_amdgcn_mfma_f32_16x16x32_bf16(af, b0, acc0, 0, 0, 0);
        acc1 = __builtin_amdgcn_mfma_f32_16x16x32_bf16(af, b1, acc1, 0, 0, 0);
        acc2 = __builtin_amdgcn_mfma_f32_16x16x32_bf16(af, b2, acc2, 0, 0, 0);
        acc3 = __builtin_amdgcn_mfma_f32_16x16x32_bf16(af, b3, acc3, 0, 0, 0);
    }

    const float inv = KLOG2E / (float)DD;
    int i0l = 16 * w + (l >> 4) * 4;              // 4 consecutive local rows
    float4 xx = *(const float4*)&x2s[i0l];
    float yy0 = y2s[c0];
    float yy1 = y2s[16 + c0];
    float yy2 = y2s[32 + c0];
    float yy3 = y2s[48 + c0];

    __syncthreads();           // all frag reads done; smem becomes Ls4

    int iql = i0l >> 2;        // local quad index 0..15
    #define WRT(ACC, YY, C) do {                                               \
        int jl = 16 * (C) + c0;                                                \
        f32x4 v;                                                               \
        v[0] = (xx.x + (YY) - 2.0f * (ACC)[0]) * inv;                          \
        v[1] = (xx.y + (YY) - 2.0f * (ACC)[1]) * inv;                          \
        v[2] = (xx.z + (YY) - 2.0f * (ACC)[2]) * inv;                          \
        v[3] = (xx.w + (YY) - 2.0f * (ACC)[3]) * inv;                          \
        Ls4[LSI4(iql + jl, iql)] = v;                                          \
    } while (0)
    WRT(acc0, yy0, 0); WRT(acc1, yy1, 1); WRT(acc2, yy2, 2); WRT(acc3, yy3, 3);
    #undef WRT
    __syncthreads();

    // coalesced quad-diag store: 79 a-lines x 16 quad slots, 5/thread
    f32x4* Cdb = Cd + (size_t)b * (NA4 * NP4);
    int base_a = (ti >> 2) + tj;
    int iqbase = ti >> 2;
    #pragma unroll
    for (int k = 0; k < 5; ++k) {
        int f  = t + k * 256;
        int al = f >> 4;                   // 0..79
        int il = f & 15;
        if (al < 79 && (unsigned)(al - il) < 64u)
            Cdb[(size_t)(base_a + al) * NP4 + iqbase + il] = Ls4[LSI4(al, il)];
    }
}

// ---------------------------------------------------------------------------
// Kernel 2: soft-DTW, 2 waves x 4 rows/lane, pipelined-q (r17 machinery).
// 128 threads/batch; lane p owns rows 4p..4p+3; column j = s - (p + 15*(p>>6));
// 656 steps (was 816), per-step overhead amortized over 4 cells (was 2).
// One boundary (wave0 lane63 -> wave1 lane0) via K=16 chunk LDS ring.
// Loads: 1 x dwordx4/step, depth-8 ring, vmcnt(7). Renorm/flush per chunk.
// ---------------------------------------------------------------------------
#define RING 8
#define KCH 16
#define ESK 15
#define NITER 41   // 656 steps >= 655 needed

__global__ __launch_bounds__(128) void sdtw_diag_kernel(const f32x4* __restrict__ Cd,
                                                        float* __restrict__ part) {
    int b = blockIdx.x;
    int p = threadIdx.x;          // 0..127 (= quad-row iq)
    int l = p & 63;
    int w = p >> 6;
    int wsk = ESK * w;            // a4 = s - wsk
    int off = p + wsk;            // column: j = s - off
    const char* CbL = (const char*)Cd + (size_t)b * (NA4 * NP4 * 16) + p * 16;

    __shared__ alignas(16) f32x2 buf[2][KCH];   // 256 B (wave0 bottom pairs)

    if (p < 32) ((f32x2*)buf)[p] = f32x2{BIGK, 1.0f};
    __syncthreads();

    float ps0 = BIGK, ps1 = BIGK, ps2 = BIGK, ps3 = BIGK;  // col j-1 s
    float pq0 = 1.0f, pq1 = 1.0f, pq2 = 1.0f, pq3 = 1.0f;  // lagged q
    float nbc_s = BIGK, nbp_s = BIGK;
    float nbc_q = 1.0f, nbp_q = 1.0f;
    f32x2 carry = {BIGK, 1.0f};
    float qfl = 1.0f;
    float eu0=0,el0=0,ed0=0, eu1=0,el1=0,ed1=0;            // exp stash
    float eu2=0,el2=0,ed2=0, eu3=0,el3=0,ed3=0;

    f32x2 b0, b1, b2, b3, b4, b5, b6, b7, b8, b9, b10, b11, b12, b13, b14, b15;
    b0=b1=b2=b3=b4=b5=b6=b7=b8=b9=b10=b11=b12=b13=b14=b15 = f32x2{BIGK, 1.0f};

    f32x4 rq0, rq1, rq2, rq3, rq4, rq5, rq6, rq7;

#define LOADPD(REG, AV) do {                                                   \
    int a_ = (AV);                                                             \
    a_ = a_ < 0 ? 0 : (a_ > NA4 - 1 ? NA4 - 1 : a_);                           \
    const char* pa_ = CbL + (unsigned)a_ * (NP4 * 16u);                        \
    asm volatile("global_load_dwordx4 %0, %1, off"                             \
                 : "=&v"(REG) : "v"(pa_) : "memory");                          \
} while (0)

    LOADPD(rq0, 0 - wsk); LOADPD(rq1, 1 - wsk); LOADPD(rq2, 2 - wsk);
    LOADPD(rq3, 3 - wsk); LOADPD(rq4, 4 - wsk); LOADPD(rq5, 5 - wsk);
    LOADPD(rq6, 6 - wsk); LOADPD(rq7, 7 - wsk);

#define QRES(JR, QUY, QDY) do {                                                \
    float qu_, qd_;                                                            \
    if (l == 0) {                                                              \
        if (w == 0) { qu_ = 1.0f; qd_ = 1.0f; }                                \
        else        { qu_ = (QUY); qd_ = (QDY); }                              \
    } else { qu_ = nbc_q; qd_ = nbp_q; }                                       \
    if ((unsigned)(JR) < 512u) {                                               \
        float o0 = pq0, o1 = pq1, o2 = pq2;                                    \
        pq0 = __builtin_fmaf(qu_, eu0, __builtin_fmaf(pq0, el0, qd_ * ed0));   \
        pq1 = __builtin_fmaf(pq0, eu1, __builtin_fmaf(pq1, el1, o0 * ed1));    \
        pq2 = __builtin_fmaf(pq1, eu2, __builtin_fmaf(pq2, el2, o1 * ed2));    \
        pq3 = __builtin_fmaf(pq2, eu3, __builtin_fmaf(pq3, el3, o2 * ed3));    \
    }                                                                          \
} while (0)

#define SCHAIN(CC, S_, SUX, SDX) do {                                          \
    float su_, sd_;                                                            \
    if (l == 0) {                                                              \
        if (w == 0) { su_ = BIGK; sd_ = ((S_) == 0) ? 0.0f : BIGK; }           \
        else        { su_ = (SUX); sd_ = (SDX); }                              \
    } else { su_ = nbc_s; sd_ = nbp_s; }                                       \
    if ((unsigned)j_ < 512u) {                                                 \
        float m0;                                                              \
        asm("v_min3_f32 %0, %1, %2, %3" : "=v"(m0) : "v"(su_), "v"(ps0), "v"(sd_)); \
        asm("v_exp_f32 %0, %1" : "=v"(eu0) : "v"(m0 - su_));                   \
        asm("v_exp_f32 %0, %1" : "=v"(el0) : "v"(m0 - ps0));                   \
        asm("v_exp_f32 %0, %1" : "=v"(ed0) : "v"(m0 - sd_));                   \
        float sA0 = (CC)[0] + m0;                                              \
        float m1;                                                              \
        asm("v_min3_f32 %0, %1, %2, %3" : "=v"(m1) : "v"(sA0), "v"(ps1), "v"(ps0)); \
        asm("v_exp_f32 %0, %1" : "=v"(eu1) : "v"(m1 - sA0));                   \
        asm("v_exp_f32 %0, %1" : "=v"(el1) : "v"(m1 - ps1));                   \
        asm("v_exp_f32 %0, %1" : "=v"(ed1) : "v"(m1 - ps0));                   \
        float sA1 = (CC)[1] + m1;                                              \
        float m2;                                                              \
        asm("v_min3_f32 %0, %1, %2, %3" : "=v"(m2) : "v"(sA1), "v"(ps2), "v"(ps1)); \
        asm("v_exp_f32 %0, %1" : "=v"(eu2) : "v"(m2 - sA1));                   \
        asm("v_exp_f32 %0, %1" : "=v"(el2) : "v"(m2 - ps2));                   \
        asm("v_exp_f32 %0, %1" : "=v"(ed2) : "v"(m2 - ps1));                   \
        float sA2 = (CC)[2] + m2;                                              \
        float m3;                                                              \
        asm("v_min3_f32 %0, %1, %2, %3" : "=v"(m3) : "v"(sA2), "v"(ps3), "v"(ps2)); \
        asm("v_exp_f32 %0, %1" : "=v"(eu3) : "v"(m3 - sA2));                   \
        asm("v_exp_f32 %0, %1" : "=v"(el3) : "v"(m3 - ps3));                   \
        asm("v_exp_f32 %0, %1" : "=v"(ed3) : "v"(m3 - ps2));                   \
        float sA3 = (CC)[3] + m3;                                              \
        ps0 = sA0; ps1 = sA1; ps2 = sA2; ps3 = sA3;                            \
    }                                                                          \
} while (0)

#define STEPD(REG, SIG, BSS, BSQ, SUX, SDX, QUY, QDY) do {                     \
    int s_ = sbase + (SIG);                                                    \
    int j_ = s_ - off;                                                         \
    f32x4 cc;                                                                  \
    asm volatile("s_waitcnt vmcnt(7)" : "=v"(cc) : "0"(REG));                  \
    QRES(j_ - 1, QUY, QDY);                                                    \
    BSQ.y = pq3;                                                               \
    SCHAIN(cc, s_, SUX, SDX);                                                  \
    BSS.x = ps3;                                                               \
    float shs_, shq_;                                                          \
    asm("v_mov_b32_dpp %0, %2 wave_shr:1 row_mask:0xf bank_mask:0xf\n\t"       \
        "v_mov_b32_dpp %1, %3 wave_shr:1 row_mask:0xf bank_mask:0xf"           \
        : "=v"(shs_), "=v"(shq_) : "v"(ps3), "v"(pq3));                        \
    nbp_s = nbc_s; nbc_s = shs_;                                               \
    nbp_q = nbc_q; nbc_q = shq_;                                               \
    LOADPD(REG, s_ + RING - wsk);                                              \
} while (0)

#define STEP0D(REG, BSS) do {                                                  \
    int s_ = sbase;                                                            \
    int j_ = s_ - off;                                                         \
    f32x4 cc;                                                                  \
    asm volatile("s_waitcnt vmcnt(7)" : "=v"(cc) : "0"(REG));                  \
    SCHAIN(cc, s_, c0[0], carry.x);                                            \
    BSS.x = ps3;                                                               \
    float shs_;                                                                \
    asm("v_mov_b32_dpp %0, %1 wave_shr:1 row_mask:0xf bank_mask:0xf"           \
        : "=v"(shs_) : "v"(ps3));                                              \
    nbp_s = nbc_s; nbc_s = shs_;                                               \
    nbp_q = nbc_q; nbc_q = qfl;                                                \
    LOADPD(REG, s_ + RING - wsk);                                              \
} while (0)

#define FLUSHQ() do {                                                          \
    int jr_ = sbase + 15 - off;                                                \
    QRES(jr_, c7[3], c7[1]);                                                   \
    b15.y = pq3;                                                               \
    asm("v_mov_b32_dpp %0, %1 wave_shr:1 row_mask:0xf bank_mask:0xf"           \
        : "=v"(qfl) : "v"(pq3));                                               \
} while (0)

#define RENORMD(S, Q) do {                                                     \
    int e_ = (__float_as_int(Q) >> 23) - 127;                                  \
    Q = __int_as_float(__float_as_int(Q) - (e_ << 23));                        \
    S = S - (float)e_;                                                         \
} while (0)

    for (int I = 0; I < NITER; ++I) {
        asm volatile("s_waitcnt lgkmcnt(0)" ::: "memory");
        __builtin_amdgcn_s_barrier();
        asm volatile("" ::: "memory");
        const f32x4* rq = (const f32x4*)&buf[(I + 1) & 1][0];
        f32x4 c0 = rq[0], c1 = rq[1], c2 = rq[2], c3 = rq[3];
        f32x4 c4 = rq[4], c5 = rq[5], c6 = rq[6], c7 = rq[7];
        int sbase = I * KCH;
        STEP0D(rq0, b0);
        STEPD(rq1, 1,  b1,  b0,  c0[2], c0[0], c0[1], carry.y);
        STEPD(rq2, 2,  b2,  b1,  c1[0], c0[2], c0[3], c0[1]);
        STEPD(rq3, 3,  b3,  b2,  c1[2], c1[0], c1[1], c0[3]);
        STEPD(rq4, 4,  b4,  b3,  c2[0], c1[2], c1[3], c1[1]);
        STEPD(rq5, 5,  b5,  b4,  c2[2], c2[0], c2[1], c1[3]);
        STEPD(rq6, 6,  b6,  b5,  c3[0], c2[2], c2[3], c2[1]);
        STEPD(rq7, 7,  b7,  b6,  c3[2], c3[0], c3[1], c2[3]);
        STEPD(rq0, 8,  b8,  b7,  c4[0], c3[2], c3[3], c3[1]);
        STEPD(rq1, 9,  b9,  b8,  c4[2], c4[0], c4[1], c3[3]);
        STEPD(rq2, 10, b10, b9,  c5[0], c4[2], c4[3], c4[1]);
        STEPD(rq3, 11, b11, b10, c5[2], c5[0], c5[1], c4[3]);
        STEPD(rq4, 12, b12, b11, c6[0], c5[2], c5[3], c5[1]);
        STEPD(rq5, 13, b13, b12, c6[2], c6[0], c6[1], c5[3]);
        STEPD(rq6, 14, b14, b13, c7[0], c6[2], c6[3], c6[1]);
        STEPD(rq7, 15, b15, b14, c7[2], c7[0], c7[1], c6[3]);
        FLUSHQ();
        carry = f32x2{c7[2], c7[3]};
        if (p == 63) {   // wave0 lane63 = producer
            f32x2* wbp = &buf[I & 1][0];
            wbp[0]  = b0;  wbp[1]  = b1;  wbp[2]  = b2;  wbp[3]  = b3;
            wbp[4]  = b4;  wbp[5]  = b5;  wbp[6]  = b6;  wbp[7]  = b7;
            wbp[8]  = b8;  wbp[9]  = b9;  wbp[10] = b10; wbp[11] = b11;
            wbp[12] = b12; wbp[13] = b13; wbp[14] = b14; wbp[15] = b15;
        }
        RENORMD(ps0, pq0);
        RENORMD(ps1, pq1);
        RENORMD(ps2, pq2);
        RENORMD(ps3, pq3);
    }

    if (p == 127) {   // row 511 = quad 127 row 3
        float lg;
        asm("v_log_f32 %0, %1" : "=v"(lg) : "v"(pq3));
        part[b] = (ps3 - lg) * LN2F;
    }
#undef STEPD
#undef STEP0D
#undef FLUSHQ
#undef QRES
#undef SCHAIN
#undef LOADPD
#undef RENORMD
}

// ---------------------------------------------------------------------------
// Kernel 3: one-wave deterministic reduction. out = sum_b(R_b) / (B * N)
// ---------------------------------------------------------------------------
__global__ __launch_bounds__(64) void reduce_kernel(const float* __restrict__ part,
                                                    float* __restrict__ out) {
    int l = threadIdx.x;
    float v = part[l];
    #pragma unroll
    for (int m = 32; m >= 1; m >>= 1) v += __shfl_xor(v, m, 64);
    if (l == 0) out[0] = v / (float)(BATCH * NN);
}

// ---------------------------------------------------------------------------
extern "C" void kernel_launch(void* const* d_in, const int* in_sizes, int n_in,
                              void* d_out, int out_size, void* d_ws, size_t ws_size,
                              hipStream_t stream) {
    const float* X = (const float*)d_in[0];
    const float* Y = (const float*)d_in[1];
    float* out = (float*)d_out;
    char* ws = (char*)d_ws;

    const size_t cdBytes = (size_t)BATCH * NA4 * NP4 * 16;    // 84 MiB

    f32x4* Cd   = (f32x4*)ws;
    float* part = (float*)(ws + cdBytes);

    dim3 g(MM / 64, NN / 64, BATCH);
    cost_diag_mfma<<<g, 256, 0, stream>>>(X, Y, Cd);

    sdtw_diag_kernel<<<BATCH, 128, 0, stream>>>(Cd, part);

    reduce_kernel<<<1, 64, 0, stream>>>(part, out);
}

// Round 19
// 150.157 us; speedup vs baseline: 1.0964x; 1.0964x over previous
//
#include <hip/hip_runtime.h>
#include <hip/hip_fp16.h>
#include <math.h>

#define BATCH 64
#define NN 512
#define MM 512
#define DD 128
#define BIGF 1e30f
#define KLOG2E 1.442695040888963f
#define LN2F   0.693147180559945f
#define BIGK   (BIGF * KLOG2E)

#define NA 768          // padded pair-antidiagonal count
#define NP 256          // pair-rows per batch

typedef __attribute__((ext_vector_type(2))) float f32x2;
typedef __attribute__((ext_vector_type(4))) float f32x4;
typedef __attribute__((ext_vector_type(8))) short s16x8;

// ---------------------------------------------------------------------------
// Kernel 1: FUSED cost GEMM (bf16 MFMA cross-term + exact fp32 row norms)
// -> diagonal-major HALF2 pairs (48 MB, was 96 MB f32 — kernel is
// write-bound, so this halves its dominant cost):
//   Cd[b][a][ip] = half2{ C[2ip][a-ip], C[2ip+1][a-ip] } * (log2e/D)
// fp16 error ~1e-3/cell -> ~2e-3 worst-case on the final scalar (thr 2.5e-2).
// Block (0,0,0) also zeroes the cross-kernel reduce counter (visible to the
// sdtw kernel via stream serialization).
// ---------------------------------------------------------------------------
__device__ __forceinline__ unsigned short f2bf(float f) {
    unsigned u = __float_as_uint(f);
    u += 0x7FFFu + ((u >> 16) & 1u);   // round-to-nearest-even
    return (unsigned short)(u >> 16);
}

#define LSI(A, IP) ((A) * 32 + ((IP) ^ ((A) & 31)))

__global__ __launch_bounds__(256) void cost_diag_mfma(const float* __restrict__ X,
                                                      const float* __restrict__ Y,
                                                      unsigned* __restrict__ Cd,
                                                      unsigned* __restrict__ cnt) {
    __shared__ alignas(16) short smem[2 * 64 * 128];   // 32 KB: Xbf | Ybf
    __shared__ float x2s[64];
    __shared__ float y2s[64];
    short* Xbf = smem;
    short* Ybf = smem + 64 * 128;
    unsigned* Ls = (unsigned*)smem;                    // reused post-MFMA (12 KB)

    int b  = blockIdx.z;
    int ti = blockIdx.y * 64;
    int tj = blockIdx.x * 64;
    int t  = threadIdx.x;
    int l  = t & 63;
    int w  = t >> 6;

    if (b == 0 && ti == 0 && tj == 0 && t == 0) *cnt = 0u;  // reduce counter

    const float* Xb = X + ((size_t)b * NN + ti) * DD;
    const float* Yb = Y + ((size_t)b * MM + tj) * DD;

    int rw  = t >> 4;          // 0..15
    int k8l = t & 15;          // 16B slot (8 bf16)
    float xs_acc[4], ys_acc[4];
    #pragma unroll
    for (int it = 0; it < 4; ++it) {
        int r = rw + it * 16;
        const float* sx = Xb + (size_t)r * DD + k8l * 8;
        const float* sy = Yb + (size_t)r * DD + k8l * 8;
        float4 x0 = *(const float4*)sx;
        float4 x1 = *(const float4*)(sx + 4);
        float4 y0 = *(const float4*)sy;
        float4 y1 = *(const float4*)(sy + 4);
        xs_acc[it] = x0.x*x0.x + x0.y*x0.y + x0.z*x0.z + x0.w*x0.w
                   + x1.x*x1.x + x1.y*x1.y + x1.z*x1.z + x1.w*x1.w;
        ys_acc[it] = y0.x*y0.x + y0.y*y0.y + y0.z*y0.z + y0.w*y0.w
                   + y1.x*y1.x + y1.y*y1.y + y1.z*y1.z + y1.w*y1.w;
        s16x8 xv, yv;
        xv[0] = (short)f2bf(x0.x); xv[1] = (short)f2bf(x0.y);
        xv[2] = (short)f2bf(x0.z); xv[3] = (short)f2bf(x0.w);
        xv[4] = (short)f2bf(x1.x); xv[5] = (short)f2bf(x1.y);
        xv[6] = (short)f2bf(x1.z); xv[7] = (short)f2bf(x1.w);
        yv[0] = (short)f2bf(y0.x); yv[1] = (short)f2bf(y0.y);
        yv[2] = (short)f2bf(y0.z); yv[3] = (short)f2bf(y0.w);
        yv[4] = (short)f2bf(y1.x); yv[5] = (short)f2bf(y1.y);
        yv[6] = (short)f2bf(y1.z); yv[7] = (short)f2bf(y1.w);
        int sw = (r * 16 + (k8l ^ (r & 7))) * 8;
        *(s16x8*)&Xbf[sw] = xv;
        *(s16x8*)&Ybf[sw] = yv;
    }
    #pragma unroll
    for (int it = 0; it < 4; ++it) {
        float xs = xs_acc[it], ys = ys_acc[it];
        #pragma unroll
        for (int m = 8; m >= 1; m >>= 1) {
            xs += __shfl_xor(xs, m, 16);
            ys += __shfl_xor(ys, m, 16);
        }
        if (k8l == 0) { x2s[rw + it * 16] = xs; y2s[rw + it * 16] = ys; }
    }
    __syncthreads();

    f32x4 acc0 = {0.f,0.f,0.f,0.f}, acc1 = acc0, acc2 = acc0, acc3 = acc0;
    int ar = 16 * w + (l & 15);
    int kb = l >> 4;           // 0..3
    int c0 = l & 15;
    #pragma unroll
    for (int kk = 0; kk < 4; ++kk) {
        int k8 = kk * 4 + kb;
        s16x8 af = *(const s16x8*)&Xbf[(ar * 16 + (k8 ^ (ar & 7))) * 8];
        s16x8 b0 = *(const s16x8*)&Ybf[((c0     ) * 16 + (k8 ^ ((c0     ) & 7))) * 8];
        s16x8 b1 = *(const s16x8*)&Ybf[((c0 + 16) * 16 + (k8 ^ ((c0 + 16) & 7))) * 8];
        s16x8 b2 = *(const s16x8*)&Ybf[((c0 + 32) * 16 + (k8 ^ ((c0 + 32) & 7))) * 8];
        s16x8 b3 = *(const s16x8*)&Ybf[((c0 + 48) * 16 + (k8 ^ ((c0 + 48) & 7))) * 8];
        acc0 = __builtin_amdgcn_mfma_f32_16x16x32_bf16(af, b0, acc0, 0, 0, 0);
        acc1 = __builtin_amdgcn_mfma_f32_16x16x32_bf16(af, b1, acc1, 0, 0, 0);
        acc2 = __builtin_amdgcn_mfma_f32_16x16x32_bf16(af, b2, acc2, 0, 0, 0);
        acc3 = __builtin_amdgcn_mfma_f32_16x16x32_bf16(af, b3, acc3, 0, 0, 0);
    }

    const float inv = KLOG2E / (float)DD;
    int i0l = 16 * w + (l >> 4) * 4;
    float4 xx = *(const float4*)&x2s[i0l];
    float yy0 = y2s[c0];
    float yy1 = y2s[16 + c0];
    float yy2 = y2s[32 + c0];
    float yy3 = y2s[48 + c0];

    __syncthreads();           // all frag reads done; smem becomes Ls

    int ipl0 = i0l >> 1;
    #define WRT(ACC, YY, C) do {                                               \
        int jl = 16 * (C) + c0;                                                \
        float v0 = (xx.x + (YY) - 2.0f * (ACC)[0]) * inv;                      \
        float v1 = (xx.y + (YY) - 2.0f * (ACC)[1]) * inv;                      \
        float v2 = (xx.z + (YY) - 2.0f * (ACC)[2]) * inv;                      \
        float v3 = (xx.w + (YY) - 2.0f * (ACC)[3]) * inv;                      \
        __half2 h01 = __floats2half2_rn(v0, v1);                               \
        __half2 h23 = __floats2half2_rn(v2, v3);                               \
        Ls[LSI(ipl0 + jl, ipl0)]         = *(unsigned*)&h01;                   \
        Ls[LSI(ipl0 + 1 + jl, ipl0 + 1)] = *(unsigned*)&h23;                   \
    } while (0)
    WRT(acc0, yy0, 0); WRT(acc1, yy1, 1); WRT(acc2, yy2, 2); WRT(acc3, yy3, 3);
    #undef WRT
    __syncthreads();

    // coalesced diag store: 96 a-lines x 32 pair slots, 12/thread (4B each)
    unsigned* Cdb = Cd + (size_t)b * (NA * NP);
    int base_a = (ti >> 1) + tj;
    int ipbase = (ti >> 1);
    #pragma unroll
    for (int k = 0; k < 12; ++k) {
        int f  = t + k * 256;
        int al = f >> 5;                   // 0..95
        int il = f & 31;
        int d  = al - il;                  // = local j
        if ((unsigned)d < 64u)
            Cdb[(size_t)(base_a + al) * NP + ipbase + il] = Ls[LSI(al, il)];
    }
}

// ---------------------------------------------------------------------------
// Kernel 2: soft-DTW (r17 structure verbatim: 4 waves x 2 rows/lane,
// pipelined-q, DPP handoff, K=16 chunks, depth-8 asm ring). Changes:
// (a) Cd is half2 -> dword loads + 2x v_cvt_f32_f16 per step;
// (b) fused final reduction: p==255 writes part[b], threadfence, ACQ_REL
//     atomic inc; the 64th signer sums part[0..63] in fixed order -> out.
// ---------------------------------------------------------------------------
#define RING 8
#define KCH 16
#define ESK 15
#define NITER 51   // 816 steps >= 812 needed

__global__ __launch_bounds__(256) void sdtw_diag_kernel(const unsigned* __restrict__ Cd,
                                                        float* __restrict__ part,
                                                        float* __restrict__ out,
                                                        unsigned* __restrict__ cnt) {
    int b = blockIdx.x;
    int p = threadIdx.x;          // 0..255 (= pair-row ip)
    int l = p & 63;
    int w = p >> 6;
    int wm1 = (w == 0) ? 0 : (w - 1);
    int wsk = ESK * w;            // a = s - wsk
    int off = p + wsk;            // column: j = s - off
    const char* CbL = (const char*)Cd + (size_t)b * (NA * NP * 4) + p * 4;

    __shared__ alignas(16) f32x2 buf[2][4][KCH];   // 1 KB

    if (p < 128) ((f32x2*)buf)[p] = f32x2{BIGK, 1.0f};
    __syncthreads();

    float ps0 = BIGK, pq0 = 1.0f;      // row 2p   s at col j-1 / lagged q
    float ps1 = BIGK, pq1 = 1.0f;      // row 2p+1
    float nbc_s = BIGK, nbc_q = 1.0f;  // dpp up pair (s leads q by one col)
    float nbp_s = BIGK, nbp_q = 1.0f;
    f32x2 carry = {BIGK, 1.0f};        // prev-chunk slot15 (s,q)
    float qfl = 1.0f;                  // flush-shuffled neighbor q
    float eS = 0.f, lS = 0.f, dS = 0.f, fS = 0.f, gS = 0.f, hS = 0.f; // stash

    f32x2 b0, b1, b2, b3, b4, b5, b6, b7, b8, b9, b10, b11, b12, b13, b14, b15;
    b0=b1=b2=b3=b4=b5=b6=b7=b8=b9=b10=b11=b12=b13=b14=b15 = f32x2{BIGK, 1.0f};

    unsigned r0, r1, r2, r3, r4, r5, r6, r7;

#define LOADPD(REG, AV) do {                                                   \
    int a_ = (AV);                                                             \
    a_ = a_ < 0 ? 0 : (a_ > NA - 1 ? NA - 1 : a_);                             \
    const char* pa_ = CbL + (unsigned)a_ * (NP * 4u);                          \
    asm volatile("global_load_dword %0, %1, off"                               \
                 : "=&v"(REG) : "v"(pa_) : "memory");                          \
} while (0)

    LOADPD(r0, 0 - wsk); LOADPD(r1, 1 - wsk); LOADPD(r2, 2 - wsk);
    LOADPD(r3, 3 - wsk); LOADPD(r4, 4 - wsk); LOADPD(r5, 5 - wsk);
    LOADPD(r6, 6 - wsk); LOADPD(r7, 7 - wsk);

#define SCHAIN(CC, S_, SUX, SDX) do {                                          \
    float su_, sd_;                                                            \
    if (l == 0) {                                                              \
        if (w == 0) { su_ = BIGK; sd_ = ((S_) == 0) ? 0.0f : BIGK; }           \
        else        { su_ = (SUX); sd_ = (SDX); }                              \
    } else { su_ = nbc_s; sd_ = nbp_s; }                                       \
    if ((unsigned)j_ < 512u) {                                                 \
        float lAs = ps0;                                                       \
        float m1;                                                              \
        asm("v_min3_f32 %0, %1, %2, %3" : "=v"(m1) : "v"(su_), "v"(lAs), "v"(sd_)); \
        asm("v_exp_f32 %0, %1" : "=v"(eS) : "v"(m1 - su_));                    \
        asm("v_exp_f32 %0, %1" : "=v"(lS) : "v"(m1 - lAs));                    \
        asm("v_exp_f32 %0, %1" : "=v"(dS) : "v"(m1 - sd_));                    \
        float sA = (CC).x + m1;                                                \
        float m2;                                                              \
        asm("v_min3_f32 %0, %1, %2, %3" : "=v"(m2) : "v"(sA), "v"(ps1), "v"(lAs)); \
        asm("v_exp_f32 %0, %1" : "=v"(fS) : "v"(m2 - sA));                     \
        asm("v_exp_f32 %0, %1" : "=v"(gS) : "v"(m2 - ps1));                    \
        asm("v_exp_f32 %0, %1" : "=v"(hS) : "v"(m2 - lAs));                    \
        ps0 = sA;                                                              \
        ps1 = (CC).y + m2;                                                     \
    }                                                                          \
} while (0)

#define QRESOLVE(JR, QUY, QDY) do {                                            \
    float qu_, qd_;                                                            \
    if (l == 0) {                                                              \
        if (w == 0) { qu_ = 1.0f; qd_ = 1.0f; }                                \
        else        { qu_ = (QUY); qd_ = (QDY); }                              \
    } else { qu_ = nbc_q; qd_ = nbp_q; }                                       \
    if ((unsigned)(JR) < 512u) {                                               \
        float qAo = pq0;                                                       \
        float qA = __builtin_fmaf(qu_, eS, __builtin_fmaf(pq0, lS, qd_ * dS)); \
        float qB = __builtin_fmaf(qA, fS, __builtin_fmaf(pq1, gS, qAo * hS));  \
        pq0 = qA; pq1 = qB;                                                    \
    }                                                                          \
} while (0)

#define STEPN(REG, SIG, BSS, BSQ, SUX, SDX, QUY, QDY) do {                     \
    int s_ = sbase + (SIG);                                                    \
    int j_ = s_ - off;                                                         \
    unsigned bits_;                                                            \
    asm volatile("s_waitcnt vmcnt(7)" : "=v"(bits_) : "0"(REG));               \
    __half2 h_ = *(__half2*)&bits_;                                            \
    f32x2 cc;                                                                  \
    cc.x = __low2float(h_); cc.y = __high2float(h_);                           \
    QRESOLVE(j_ - 1, QUY, QDY);                                                \
    BSQ.y = pq1;                                                               \
    SCHAIN(cc, s_, SUX, SDX);                                                  \
    BSS.x = ps1;                                                               \
    float shs_, shq_;                                                          \
    asm("v_mov_b32_dpp %0, %2 wave_shr:1 row_mask:0xf bank_mask:0xf\n\t"       \
        "v_mov_b32_dpp %1, %3 wave_shr:1 row_mask:0xf bank_mask:0xf"           \
        : "=v"(shs_), "=v"(shq_) : "v"(ps1), "v"(pq1));                        \
    nbp_s = nbc_s; nbc_s = shs_;                                               \
    nbp_q = nbc_q; nbc_q = shq_;                                               \
    LOADPD(REG, s_ + RING - wsk);                                              \
} while (0)

#define STEP0(REG, BSS) do {                                                   \
    int s_ = sbase;                                                            \
    int j_ = s_ - off;                                                         \
    unsigned bits_;                                                            \
    asm volatile("s_waitcnt vmcnt(7)" : "=v"(bits_) : "0"(REG));               \
    __half2 h_ = *(__half2*)&bits_;                                            \
    f32x2 cc;                                                                  \
    cc.x = __low2float(h_); cc.y = __high2float(h_);                           \
    SCHAIN(cc, s_, c0[0], carry.x);                                            \
    BSS.x = ps1;                                                               \
    float shs_;                                                                \
    asm("v_mov_b32_dpp %0, %1 wave_shr:1 row_mask:0xf bank_mask:0xf"           \
        : "=v"(shs_) : "v"(ps1));                                              \
    nbp_s = nbc_s; nbc_s = shs_;                                               \
    nbp_q = nbc_q; nbc_q = qfl;                                                \
    LOADPD(REG, s_ + RING - wsk);                                              \
} while (0)

#define FLUSHQ() do {                                                          \
    int jr_ = sbase + 15 - off;                                                \
    QRESOLVE(jr_, c7[3], c7[1]);                                               \
    b15.y = pq1;                                                               \
    asm("v_mov_b32_dpp %0, %1 wave_shr:1 row_mask:0xf bank_mask:0xf"           \
        : "=v"(qfl) : "v"(pq1));                                               \
} while (0)

#define RENORMD(S, Q) do {                                                     \
    int e_ = (__float_as_int(Q) >> 23) - 127;                                  \
    Q = __int_as_float(__float_as_int(Q) - (e_ << 23));                        \
    S = S - (float)e_;                                                         \
} while (0)

    for (int I = 0; I < NITER; ++I) {
        asm volatile("s_waitcnt lgkmcnt(0)" ::: "memory");
        __builtin_amdgcn_s_barrier();
        asm volatile("" ::: "memory");
        const f32x4* rq = (const f32x4*)&buf[(I + 1) & 1][wm1][0];
        f32x4 c0 = rq[0], c1 = rq[1], c2 = rq[2], c3 = rq[3];
        f32x4 c4 = rq[4], c5 = rq[5], c6 = rq[6], c7 = rq[7];
        int sbase = I * KCH;
        STEP0(r0, b0);
        STEPN(r1, 1,  b1,  b0,  c0[2], c0[0], c0[1], carry.y);
        STEPN(r2, 2,  b2,  b1,  c1[0], c0[2], c0[3], c0[1]);
        STEPN(r3, 3,  b3,  b2,  c1[2], c1[0], c1[1], c0[3]);
        STEPN(r4, 4,  b4,  b3,  c2[0], c1[2], c1[3], c1[1]);
        STEPN(r5, 5,  b5,  b4,  c2[2], c2[0], c2[1], c1[3]);
        STEPN(r6, 6,  b6,  b5,  c3[0], c2[2], c2[3], c2[1]);
        STEPN(r7, 7,  b7,  b6,  c3[2], c3[0], c3[1], c2[3]);
        STEPN(r0, 8,  b8,  b7,  c4[0], c3[2], c3[3], c3[1]);
        STEPN(r1, 9,  b9,  b8,  c4[2], c4[0], c4[1], c3[3]);
        STEPN(r2, 10, b10, b9,  c5[0], c4[2], c4[3], c4[1]);
        STEPN(r3, 11, b11, b10, c5[2], c5[0], c5[1], c4[3]);
        STEPN(r4, 12, b12, b11, c6[0], c5[2], c5[3], c5[1]);
        STEPN(r5, 13, b13, b12, c6[2], c6[0], c6[1], c5[3]);
        STEPN(r6, 14, b14, b13, c7[0], c6[2], c6[3], c6[1]);
        STEPN(r7, 15, b15, b14, c7[2], c7[0], c7[1], c6[3]);
        FLUSHQ();
        carry = f32x2{c7[2], c7[3]};
        if (l == 63) {
            f32x2* wbp = &buf[I & 1][w][0];
            wbp[0]  = b0;  wbp[1]  = b1;  wbp[2]  = b2;  wbp[3]  = b3;
            wbp[4]  = b4;  wbp[5]  = b5;  wbp[6]  = b6;  wbp[7]  = b7;
            wbp[8]  = b8;  wbp[9]  = b9;  wbp[10] = b10; wbp[11] = b11;
            wbp[12] = b12; wbp[13] = b13; wbp[14] = b14; wbp[15] = b15;
        }
        RENORMD(ps0, pq0);
        RENORMD(ps1, pq1);
    }

    if (p == 255) {   // cell (511,511): resolved in-loop; fused reduction
        float lg;
        asm("v_log_f32 %0, %1" : "=v"(lg) : "v"(pq1));
        part[b] = (ps1 - lg) * LN2F;
        __threadfence();
        unsigned prev = __hip_atomic_fetch_add(cnt, 1u, __ATOMIC_ACQ_REL,
                                               __HIP_MEMORY_SCOPE_AGENT);
        if (prev == BATCH - 1u) {          // last block: deterministic sum
            const volatile float* vp = part;
            float s = 0.0f;
            #pragma unroll
            for (int i = 0; i < BATCH; ++i) s += vp[i];
            out[0] = s / (float)(BATCH * NN);
        }
    }
#undef STEPN
#undef STEP0
#undef FLUSHQ
#undef QRESOLVE
#undef SCHAIN
#undef LOADPD
#undef RENORMD
}

// ---------------------------------------------------------------------------
extern "C" void kernel_launch(void* const* d_in, const int* in_sizes, int n_in,
                              void* d_out, int out_size, void* d_ws, size_t ws_size,
                              hipStream_t stream) {
    const float* X = (const float*)d_in[0];
    const float* Y = (const float*)d_in[1];
    float* out = (float*)d_out;
    char* ws = (char*)d_ws;

    const size_t cdBytes = (size_t)BATCH * NA * NP * 4;       // 48 MiB (half2)

    unsigned* Cd   = (unsigned*)ws;
    float*    part = (float*)(ws + cdBytes);
    unsigned* cnt  = (unsigned*)(ws + cdBytes + 256);

    dim3 g(MM / 64, NN / 64, BATCH);
    cost_diag_mfma<<<g, 256, 0, stream>>>(X, Y, Cd, cnt);

    sdtw_diag_kernel<<<BATCH, 256, 0, stream>>>(Cd, part, out, cnt);
}

// Round 20
// 149.348 us; speedup vs baseline: 1.1023x; 1.0054x over previous
//
#include <hip/hip_runtime.h>
#include <hip/hip_fp16.h>
#include <math.h>

#define BATCH 64
#define NN 512
#define MM 512
#define DD 128
#define BIGF 1e30f
#define KLOG2E 1.442695040888963f
#define LN2F   0.693147180559945f
#define BIGK   (BIGF * KLOG2E)

#define NA 768          // padded pair-antidiagonal count
#define NP 256          // pair-rows per batch

typedef __attribute__((ext_vector_type(2))) float f32x2;
typedef __attribute__((ext_vector_type(4))) float f32x4;
typedef __attribute__((ext_vector_type(8))) short s16x8;

// ---------------------------------------------------------------------------
// Kernel 1: FUSED cost GEMM (bf16 MFMA cross-term + exact fp32 row norms)
// -> diagonal-major HALF2 pairs (48 MB). Unchanged from r19.
// Block (0,0,0) zeroes the cross-kernel reduce counter.
// ---------------------------------------------------------------------------
__device__ __forceinline__ unsigned short f2bf(float f) {
    unsigned u = __float_as_uint(f);
    u += 0x7FFFu + ((u >> 16) & 1u);   // round-to-nearest-even
    return (unsigned short)(u >> 16);
}

#define LSI(A, IP) ((A) * 32 + ((IP) ^ ((A) & 31)))

__global__ __launch_bounds__(256) void cost_diag_mfma(const float* __restrict__ X,
                                                      const float* __restrict__ Y,
                                                      unsigned* __restrict__ Cd,
                                                      unsigned* __restrict__ cnt) {
    __shared__ alignas(16) short smem[2 * 64 * 128];   // 32 KB: Xbf | Ybf
    __shared__ float x2s[64];
    __shared__ float y2s[64];
    short* Xbf = smem;
    short* Ybf = smem + 64 * 128;
    unsigned* Ls = (unsigned*)smem;                    // reused post-MFMA (12 KB)

    int b  = blockIdx.z;
    int ti = blockIdx.y * 64;
    int tj = blockIdx.x * 64;
    int t  = threadIdx.x;
    int l  = t & 63;
    int w  = t >> 6;

    if (b == 0 && ti == 0 && tj == 0 && t == 0) *cnt = 0u;  // reduce counter

    const float* Xb = X + ((size_t)b * NN + ti) * DD;
    const float* Yb = Y + ((size_t)b * MM + tj) * DD;

    int rw  = t >> 4;          // 0..15
    int k8l = t & 15;          // 16B slot (8 bf16)
    float xs_acc[4], ys_acc[4];
    #pragma unroll
    for (int it = 0; it < 4; ++it) {
        int r = rw + it * 16;
        const float* sx = Xb + (size_t)r * DD + k8l * 8;
        const float* sy = Yb + (size_t)r * DD + k8l * 8;
        float4 x0 = *(const float4*)sx;
        float4 x1 = *(const float4*)(sx + 4);
        float4 y0 = *(const float4*)sy;
        float4 y1 = *(const float4*)(sy + 4);
        xs_acc[it] = x0.x*x0.x + x0.y*x0.y + x0.z*x0.z + x0.w*x0.w
                   + x1.x*x1.x + x1.y*x1.y + x1.z*x1.z + x1.w*x1.w;
        ys_acc[it] = y0.x*y0.x + y0.y*y0.y + y0.z*y0.z + y0.w*y0.w
                   + y1.x*y1.x + y1.y*y1.y + y1.z*y1.z + y1.w*y1.w;
        s16x8 xv, yv;
        xv[0] = (short)f2bf(x0.x); xv[1] = (short)f2bf(x0.y);
        xv[2] = (short)f2bf(x0.z); xv[3] = (short)f2bf(x0.w);
        xv[4] = (short)f2bf(x1.x); xv[5] = (short)f2bf(x1.y);
        xv[6] = (short)f2bf(x1.z); xv[7] = (short)f2bf(x1.w);
        yv[0] = (short)f2bf(y0.x); yv[1] = (short)f2bf(y0.y);
        yv[2] = (short)f2bf(y0.z); yv[3] = (short)f2bf(y0.w);
        yv[4] = (short)f2bf(y1.x); yv[5] = (short)f2bf(y1.y);
        yv[6] = (short)f2bf(y1.z); yv[7] = (short)f2bf(y1.w);
        int sw = (r * 16 + (k8l ^ (r & 7))) * 8;
        *(s16x8*)&Xbf[sw] = xv;
        *(s16x8*)&Ybf[sw] = yv;
    }
    #pragma unroll
    for (int it = 0; it < 4; ++it) {
        float xs = xs_acc[it], ys = ys_acc[it];
        #pragma unroll
        for (int m = 8; m >= 1; m >>= 1) {
            xs += __shfl_xor(xs, m, 16);
            ys += __shfl_xor(ys, m, 16);
        }
        if (k8l == 0) { x2s[rw + it * 16] = xs; y2s[rw + it * 16] = ys; }
    }
    __syncthreads();

    f32x4 acc0 = {0.f,0.f,0.f,0.f}, acc1 = acc0, acc2 = acc0, acc3 = acc0;
    int ar = 16 * w + (l & 15);
    int kb = l >> 4;           // 0..3
    int c0 = l & 15;
    #pragma unroll
    for (int kk = 0; kk < 4; ++kk) {
        int k8 = kk * 4 + kb;
        s16x8 af = *(const s16x8*)&Xbf[(ar * 16 + (k8 ^ (ar & 7))) * 8];
        s16x8 b0 = *(const s16x8*)&Ybf[((c0     ) * 16 + (k8 ^ ((c0     ) & 7))) * 8];
        s16x8 b1 = *(const s16x8*)&Ybf[((c0 + 16) * 16 + (k8 ^ ((c0 + 16) & 7))) * 8];
        s16x8 b2 = *(const s16x8*)&Ybf[((c0 + 32) * 16 + (k8 ^ ((c0 + 32) & 7))) * 8];
        s16x8 b3 = *(const s16x8*)&Ybf[((c0 + 48) * 16 + (k8 ^ ((c0 + 48) & 7))) * 8];
        acc0 = __builtin_amdgcn_mfma_f32_16x16x32_bf16(af, b0, acc0, 0, 0, 0);
        acc1 = __builtin_amdgcn_mfma_f32_16x16x32_bf16(af, b1, acc1, 0, 0, 0);
        acc2 = __builtin_amdgcn_mfma_f32_16x16x32_bf16(af, b2, acc2, 0, 0, 0);
        acc3 = __builtin_amdgcn_mfma_f32_16x16x32_bf16(af, b3, acc3, 0, 0, 0);
    }

    const float inv = KLOG2E / (float)DD;
    int i0l = 16 * w + (l >> 4) * 4;
    float4 xx = *(const float4*)&x2s[i0l];
    float yy0 = y2s[c0];
    float yy1 = y2s[16 + c0];
    float yy2 = y2s[32 + c0];
    float yy3 = y2s[48 + c0];

    __syncthreads();           // all frag reads done; smem becomes Ls

    int ipl0 = i0l >> 1;
    #define WRT(ACC, YY, C) do {                                               \
        int jl = 16 * (C) + c0;                                                \
        float v0 = (xx.x + (YY) - 2.0f * (ACC)[0]) * inv;                      \
        float v1 = (xx.y + (YY) - 2.0f * (ACC)[1]) * inv;                      \
        float v2 = (xx.z + (YY) - 2.0f * (ACC)[2]) * inv;                      \
        float v3 = (xx.w + (YY) - 2.0f * (ACC)[3]) * inv;                      \
        __half2 h01 = __floats2half2_rn(v0, v1);                               \
        __half2 h23 = __floats2half2_rn(v2, v3);                               \
        Ls[LSI(ipl0 + jl, ipl0)]         = *(unsigned*)&h01;                   \
        Ls[LSI(ipl0 + 1 + jl, ipl0 + 1)] = *(unsigned*)&h23;                   \
    } while (0)
    WRT(acc0, yy0, 0); WRT(acc1, yy1, 1); WRT(acc2, yy2, 2); WRT(acc3, yy3, 3);
    #undef WRT
    __syncthreads();

    unsigned* Cdb = Cd + (size_t)b * (NA * NP);
    int base_a = (ti >> 1) + tj;
    int ipbase = (ti >> 1);
    #pragma unroll
    for (int k = 0; k < 12; ++k) {
        int f  = t + k * 256;
        int al = f >> 5;                   // 0..95
        int il = f & 31;
        int d  = al - il;                  // = local j
        if ((unsigned)d < 64u)
            Cdb[(size_t)(base_a + al) * NP + ipbase + il] = Ls[LSI(al, il)];
    }
}

// ---------------------------------------------------------------------------
// Kernel 2: soft-DTW (r17 structure). vs r19 (single change): fp16->f32
// decode is PIPELINED ONE STEP AHEAD. At step s: wait vmcnt(6) (retires
// slots s and s+1; 7 loads stay in flight, flight = 7 steps ~900cyc), cvt
// slot s+1 -> ccN (off-chain, fills exp stalls), consume ccP (converted at
// step s-1). Prologue: vmcnt(7) + cvt slot 0. ccP is loop-carried across
// chunk boundaries. Fused deterministic reduction kept (r19).
// ---------------------------------------------------------------------------
#define RING 8
#define KCH 16
#define ESK 15
#define NITER 51   // 816 steps >= 812 needed

__global__ __launch_bounds__(256) void sdtw_diag_kernel(const unsigned* __restrict__ Cd,
                                                        float* __restrict__ part,
                                                        float* __restrict__ out,
                                                        unsigned* __restrict__ cnt) {
    int b = blockIdx.x;
    int p = threadIdx.x;          // 0..255 (= pair-row ip)
    int l = p & 63;
    int w = p >> 6;
    int wm1 = (w == 0) ? 0 : (w - 1);
    int wsk = ESK * w;            // a = s - wsk
    int off = p + wsk;            // column: j = s - off
    const char* CbL = (const char*)Cd + (size_t)b * (NA * NP * 4) + p * 4;

    __shared__ alignas(16) f32x2 buf[2][4][KCH];   // 1 KB

    if (p < 128) ((f32x2*)buf)[p] = f32x2{BIGK, 1.0f};
    __syncthreads();

    float ps0 = BIGK, pq0 = 1.0f;      // row 2p   s at col j-1 / lagged q
    float ps1 = BIGK, pq1 = 1.0f;      // row 2p+1
    float nbc_s = BIGK, nbc_q = 1.0f;  // dpp up pair (s leads q by one col)
    float nbp_s = BIGK, nbp_q = 1.0f;
    f32x2 carry = {BIGK, 1.0f};        // prev-chunk slot15 (s,q)
    float qfl = 1.0f;                  // flush-shuffled neighbor q
    float eS = 0.f, lS = 0.f, dS = 0.f, fS = 0.f, gS = 0.f, hS = 0.f; // stash
    f32x2 ccP;                         // pre-converted cost for current step

    f32x2 b0, b1, b2, b3, b4, b5, b6, b7, b8, b9, b10, b11, b12, b13, b14, b15;
    b0=b1=b2=b3=b4=b5=b6=b7=b8=b9=b10=b11=b12=b13=b14=b15 = f32x2{BIGK, 1.0f};

    unsigned r0, r1, r2, r3, r4, r5, r6, r7;

#define LOADPD(REG, AV) do {                                                   \
    int a_ = (AV);                                                             \
    a_ = a_ < 0 ? 0 : (a_ > NA - 1 ? NA - 1 : a_);                             \
    const char* pa_ = CbL + (unsigned)a_ * (NP * 4u);                          \
    asm volatile("global_load_dword %0, %1, off"                               \
                 : "=&v"(REG) : "v"(pa_) : "memory");                          \
} while (0)

    LOADPD(r0, 0 - wsk); LOADPD(r1, 1 - wsk); LOADPD(r2, 2 - wsk);
    LOADPD(r3, 3 - wsk); LOADPD(r4, 4 - wsk); LOADPD(r5, 5 - wsk);
    LOADPD(r6, 6 - wsk); LOADPD(r7, 7 - wsk);

    {   // prologue: retire slot 0 and pre-convert it
        unsigned bits0;
        asm volatile("s_waitcnt vmcnt(7)" : "=v"(bits0) : "0"(r0));
        __half2 h0 = *(__half2*)&bits0;
        ccP.x = __low2float(h0); ccP.y = __high2float(h0);
    }

#define SCHAIN(CC, S_, SUX, SDX) do {                                          \
    float su_, sd_;                                                            \
    if (l == 0) {                                                              \
        if (w == 0) { su_ = BIGK; sd_ = ((S_) == 0) ? 0.0f : BIGK; }           \
        else        { su_ = (SUX); sd_ = (SDX); }                              \
    } else { su_ = nbc_s; sd_ = nbp_s; }                                       \
    if ((unsigned)j_ < 512u) {                                                 \
        float lAs = ps0;                                                       \
        float m1;                                                              \
        asm("v_min3_f32 %0, %1, %2, %3" : "=v"(m1) : "v"(su_), "v"(lAs), "v"(sd_)); \
        asm("v_exp_f32 %0, %1" : "=v"(eS) : "v"(m1 - su_));                    \
        asm("v_exp_f32 %0, %1" : "=v"(lS) : "v"(m1 - lAs));                    \
        asm("v_exp_f32 %0, %1" : "=v"(dS) : "v"(m1 - sd_));                    \
        float sA = (CC).x + m1;                                                \
        float m2;                                                              \
        asm("v_min3_f32 %0, %1, %2, %3" : "=v"(m2) : "v"(sA), "v"(ps1), "v"(lAs)); \
        asm("v_exp_f32 %0, %1" : "=v"(fS) : "v"(m2 - sA));                     \
        asm("v_exp_f32 %0, %1" : "=v"(gS) : "v"(m2 - ps1));                    \
        asm("v_exp_f32 %0, %1" : "=v"(hS) : "v"(m2 - lAs));                    \
        ps0 = sA;                                                              \
        ps1 = (CC).y + m2;                                                     \
    }                                                                          \
} while (0)

#define QRESOLVE(JR, QUY, QDY) do {                                            \
    float qu_, qd_;                                                            \
    if (l == 0) {                                                              \
        if (w == 0) { qu_ = 1.0f; qd_ = 1.0f; }                                \
        else        { qu_ = (QUY); qd_ = (QDY); }                              \
    } else { qu_ = nbc_q; qd_ = nbp_q; }                                       \
    if ((unsigned)(JR) < 512u) {                                               \
        float qAo = pq0;                                                       \
        float qA = __builtin_fmaf(qu_, eS, __builtin_fmaf(pq0, lS, qd_ * dS)); \
        float qB = __builtin_fmaf(qA, fS, __builtin_fmaf(pq1, gS, qAo * hS));  \
        pq0 = qA; pq1 = qB;                                                    \
    }                                                                          \
} while (0)

// step consumes ccP (slot SIG, converted last step); waits vmcnt(6) to also
// retire slot SIG+1 (in REGN); converts it off-chain; reloads REGC for SIG+8.
#define STEPN(REGC, REGN, SIG, BSS, BSQ, SUX, SDX, QUY, QDY) do {              \
    int s_ = sbase + (SIG);                                                    \
    int j_ = s_ - off;                                                         \
    unsigned bitsN_;                                                           \
    asm volatile("s_waitcnt vmcnt(6)" : "=v"(bitsN_) : "0"(REGN));             \
    __half2 hN_ = *(__half2*)&bitsN_;                                          \
    f32x2 ccN;                                                                 \
    ccN.x = __low2float(hN_); ccN.y = __high2float(hN_);                       \
    QRESOLVE(j_ - 1, QUY, QDY);                                                \
    BSQ.y = pq1;                                                               \
    SCHAIN(ccP, s_, SUX, SDX);                                                 \
    BSS.x = ps1;                                                               \
    float shs_, shq_;                                                          \
    asm("v_mov_b32_dpp %0, %2 wave_shr:1 row_mask:0xf bank_mask:0xf\n\t"       \
        "v_mov_b32_dpp %1, %3 wave_shr:1 row_mask:0xf bank_mask:0xf"           \
        : "=v"(shs_), "=v"(shq_) : "v"(ps1), "v"(pq1));                        \
    nbp_s = nbc_s; nbc_s = shs_;                                               \
    nbp_q = nbc_q; nbc_q = shq_;                                               \
    LOADPD(REGC, s_ + RING - wsk);                                             \
    ccP = ccN;                                                                 \
} while (0)

#define STEP0(REGC, REGN, BSS) do {                                            \
    int s_ = sbase;                                                            \
    int j_ = s_ - off;                                                         \
    unsigned bitsN_;                                                           \
    asm volatile("s_waitcnt vmcnt(6)" : "=v"(bitsN_) : "0"(REGN));             \
    __half2 hN_ = *(__half2*)&bitsN_;                                          \
    f32x2 ccN;                                                                 \
    ccN.x = __low2float(hN_); ccN.y = __high2float(hN_);                       \
    SCHAIN(ccP, s_, c0[0], carry.x);                                           \
    BSS.x = ps1;                                                               \
    float shs_;                                                                \
    asm("v_mov_b32_dpp %0, %1 wave_shr:1 row_mask:0xf bank_mask:0xf"           \
        : "=v"(shs_) : "v"(ps1));                                              \
    nbp_s = nbc_s; nbc_s = shs_;                                               \
    nbp_q = nbc_q; nbc_q = qfl;                                                \
    LOADPD(REGC, s_ + RING - wsk);                                             \
    ccP = ccN;                                                                 \
} while (0)

#define FLUSHQ() do {                                                          \
    int jr_ = sbase + 15 - off;                                                \
    QRESOLVE(jr_, c7[3], c7[1]);                                               \
    b15.y = pq1;                                                               \
    asm("v_mov_b32_dpp %0, %1 wave_shr:1 row_mask:0xf bank_mask:0xf"           \
        : "=v"(qfl) : "v"(pq1));                                               \
} while (0)

#define RENORMD(S, Q) do {                                                     \
    int e_ = (__float_as_int(Q) >> 23) - 127;                                  \
    Q = __int_as_float(__float_as_int(Q) - (e_ << 23));                        \
    S = S - (float)e_;                                                         \
} while (0)

    for (int I = 0; I < NITER; ++I) {
        asm volatile("s_waitcnt lgkmcnt(0)" ::: "memory");
        __builtin_amdgcn_s_barrier();
        asm volatile("" ::: "memory");
        const f32x4* rq = (const f32x4*)&buf[(I + 1) & 1][wm1][0];
        f32x4 c0 = rq[0], c1 = rq[1], c2 = rq[2], c3 = rq[3];
        f32x4 c4 = rq[4], c5 = rq[5], c6 = rq[6], c7 = rq[7];
        int sbase = I * KCH;
        STEP0(r0, r1, b0);
        STEPN(r1, r2, 1,  b1,  b0,  c0[2], c0[0], c0[1], carry.y);
        STEPN(r2, r3, 2,  b2,  b1,  c1[0], c0[2], c0[3], c0[1]);
        STEPN(r3, r4, 3,  b3,  b2,  c1[2], c1[0], c1[1], c0[3]);
        STEPN(r4, r5, 4,  b4,  b3,  c2[0], c1[2], c1[3], c1[1]);
        STEPN(r5, r6, 5,  b5,  b4,  c2[2], c2[0], c2[1], c1[3]);
        STEPN(r6, r7, 6,  b6,  b5,  c3[0], c2[2], c2[3], c2[1]);
        STEPN(r7, r0, 7,  b7,  b6,  c3[2], c3[0], c3[1], c2[3]);
        STEPN(r0, r1, 8,  b8,  b7,  c4[0], c3[2], c3[3], c3[1]);
        STEPN(r1, r2, 9,  b9,  b8,  c4[2], c4[0], c4[1], c3[3]);
        STEPN(r2, r3, 10, b10, b9,  c5[0], c4[2], c4[3], c4[1]);
        STEPN(r3, r4, 11, b11, b10, c5[2], c5[0], c5[1], c4[3]);
        STEPN(r4, r5, 12, b12, b11, c6[0], c5[2], c5[3], c5[1]);
        STEPN(r5, r6, 13, b13, b12, c6[2], c6[0], c6[1], c5[3]);
        STEPN(r6, r7, 14, b14, b13, c7[0], c6[2], c6[3], c6[1]);
        STEPN(r7, r0, 15, b15, b14, c7[2], c7[0], c7[1], c6[3]);
        FLUSHQ();
        carry = f32x2{c7[2], c7[3]};
        if (l == 63) {
            f32x2* wbp = &buf[I & 1][w][0];
            wbp[0]  = b0;  wbp[1]  = b1;  wbp[2]  = b2;  wbp[3]  = b3;
            wbp[4]  = b4;  wbp[5]  = b5;  wbp[6]  = b6;  wbp[7]  = b7;
            wbp[8]  = b8;  wbp[9]  = b9;  wbp[10] = b10; wbp[11] = b11;
            wbp[12] = b12; wbp[13] = b13; wbp[14] = b14; wbp[15] = b15;
        }
        RENORMD(ps0, pq0);
        RENORMD(ps1, pq1);
    }

    if (p == 255) {   // cell (511,511): resolved in-loop; fused reduction
        float lg;
        asm("v_log_f32 %0, %1" : "=v"(lg) : "v"(pq1));
        part[b] = (ps1 - lg) * LN2F;
        __threadfence();
        unsigned prev = __hip_atomic_fetch_add(cnt, 1u, __ATOMIC_ACQ_REL,
                                               __HIP_MEMORY_SCOPE_AGENT);
        if (prev == BATCH - 1u) {          // last block: deterministic sum
            const volatile float* vp = part;
            float s = 0.0f;
            #pragma unroll
            for (int i = 0; i < BATCH; ++i) s += vp[i];
            out[0] = s / (float)(BATCH * NN);
        }
    }
#undef STEPN
#undef STEP0
#undef FLUSHQ
#undef QRESOLVE
#undef SCHAIN
#undef LOADPD
#undef RENORMD
}

// ---------------------------------------------------------------------------
extern "C" void kernel_launch(void* const* d_in, const int* in_sizes, int n_in,
                              void* d_out, int out_size, void* d_ws, size_t ws_size,
                              hipStream_t stream) {
    const float* X = (const float*)d_in[0];
    const float* Y = (const float*)d_in[1];
    float* out = (float*)d_out;
    char* ws = (char*)d_ws;

    const size_t cdBytes = (size_t)BATCH * NA * NP * 4;       // 48 MiB (half2)

    unsigned* Cd   = (unsigned*)ws;
    float*    part = (float*)(ws + cdBytes);
    unsigned* cnt  = (unsigned*)(ws + cdBytes + 256);

    dim3 g(MM / 64, NN / 64, BATCH);
    cost_diag_mfma<<<g, 256, 0, stream>>>(X, Y, Cd, cnt);

    sdtw_diag_kernel<<<BATCH, 256, 0, stream>>>(Cd, part, out, cnt);
}